// Round 3
// baseline (495.225 us; speedup 1.0000x reference)
//
#include <hip/hip_runtime.h>

// ---------------------------------------------------------------------------
// CrossModalityCrossAttention on MI355X (gfx950). I/O: float32. Internal: bf16.
// B=4 S=4097 L=8065 D=1024 H=8 DH=64 CHUNK=64 CCS=128 n=64 chunks.
//
// R3: gemm256 now a faithful port of the verified m201 8-phase template:
//   per phase: {ds_read frags (12/4/8/0) || stage ONE half-tile (2 glds),
//               [lgkmcnt(8) if 12 reads], s_barrier, lgkmcnt(0)+SB0,
//               setprio(1), 16 MFMA (one quadrant), setprio(0), s_barrier}
//   Staging cadence (tile kt): ph1 hA0(kt+1)->buf^1, ph2 hA1(kt+1)->buf^1,
//   ph3 hB0(kt+2)->buf, ph4 hB1(kt+2)->buf. A-halves go to the opposite
//   buffer (no race window); B-halves overwrite rows whose reads retired at
//   ph2's lgkmcnt(0)+barrier. vmcnt(4) once per K-tile at ph4 (counted:
//   leaves hB(kt+2) in flight); vmcnt(0) only at kt=NT-2.
//   XOR swizzle (16B unit ^= row&7) on glds source AND ds_read (rule 21).
// ---------------------------------------------------------------------------

typedef __attribute__((ext_vector_type(8))) short bf16x8;
typedef __attribute__((ext_vector_type(4))) float f32x4;

__device__ __forceinline__ short f2bf(float x) {        // RNE (epilogues, weights)
  union { float f; unsigned u; } v; v.f = x;
  unsigned r = v.u + 0x7FFFu + ((v.u >> 16) & 1u);
  return (short)(r >> 16);
}
__device__ __forceinline__ short f2bf_r(float x) {      // round-half-up (staging)
  union { float f; unsigned u; } v; v.f = x;
  return (short)((v.u + 0x8000u) >> 16);
}
__device__ __forceinline__ float bf2f(short s) {
  union { unsigned u; float f; } v;
  v.u = ((unsigned)(unsigned short)s) << 16;
  return v.f;
}
__device__ __forceinline__ void glds16(const short* g, short* l) {
  __builtin_amdgcn_global_load_lds(
      (const __attribute__((address_space(1))) void*)g,
      (__attribute__((address_space(3))) void*)l, 16, 0, 0);
}

#define SB0 __builtin_amdgcn_sched_barrier(0)

// ---------------- weight transpose (f32 [k][n] -> bf16 [n][k]) --------------
__global__ void transpose_w(const float* __restrict__ Wq, const float* __restrict__ Wkv,
                            const float* __restrict__ Wout,
                            short* __restrict__ wqT, short* __restrict__ wkvT,
                            short* __restrict__ woutT) {
  int idx = blockIdx.x * 256 + threadIdx.x;
  if (idx < 524288) {                       // Wq (1024 x 512)
    int d = idx >> 9, e = idx & 511;
    wqT[e * 1024 + d] = f2bf(Wq[idx]);
  } else if (idx < 1572864) {               // Wkv (1024 x 1024)
    int i = idx - 524288;
    int d = i >> 10, e = i & 1023;
    wkvT[e * 1024 + d] = f2bf(Wkv[i]);
  } else if (idx < 2097152) {               // Wout (512 x 1024)
    int i = idx - 1572864;
    int k = i >> 10, e = i & 1023;
    woutT[e * 512 + k] = f2bf(Wout[i]);
  }
}

// ---------------- f32 -> bf16 conversion passes (fast path) -----------------
__global__ void conv_seq(const float* __restrict__ seq, short* __restrict__ seqb) {
  size_t e = ((size_t)blockIdx.x * 256 + threadIdx.x) * 8;   // 16,777,216 elems
  int b = (int)(e >> 22);
  int i = (int)((e >> 10) & 4095);
  int k = (int)(e & 1023);
  const float* src = seq + ((size_t)b * 4097 + 1 + i) * 1024 + k;
  f32x4 f0 = *(const f32x4*)src;
  f32x4 f1 = *(const f32x4*)(src + 4);
  bf16x8 o;
#pragma unroll
  for (int j = 0; j < 4; ++j) { o[j] = f2bf_r(f0[j]); o[j + 4] = f2bf_r(f1[j]); }
  *(bf16x8*)(seqb + e) = o;
}

__global__ void conv_ctx(const float* __restrict__ ctx, short* __restrict__ ctxb) {
  size_t e = ((size_t)blockIdx.x * 256 + threadIdx.x) * 8;   // 33,554,432 elems
  int b = (int)(e >> 23);
  int r = (int)((e >> 10) & 8191);
  int k = (int)(e & 1023);
  bf16x8 o = {0, 0, 0, 0, 0, 0, 0, 0};
  if (r >= 127) {                            // rows 0..126 are the left pad
    const float* src = ctx + ((size_t)b * 8065 + (r - 127)) * 1024 + k;
    f32x4 f0 = *(const f32x4*)src;
    f32x4 f1 = *(const f32x4*)(src + 4);
#pragma unroll
    for (int j = 0; j < 4; ++j) { o[j] = f2bf_r(f0[j]); o[j + 4] = f2bf_r(f1[j]); }
  }
  *(bf16x8*)(ctxb + e) = o;
}

// ---------------- zero the (b, 0, :) output rows (f32) ----------------------
__global__ void zero_rows(float* __restrict__ out) {
  int idx = blockIdx.x * 256 + threadIdx.x;   // 4096 total
  if (idx < 4096) out[(size_t)(idx >> 10) * (4097u * 1024u) + (idx & 1023)] = 0.f;
}

// ---------------- 256x256 m201-style 8-phase GEMM ---------------------------
// MODE 1: A = ctxb [32768][1024], B = wkvT -> kws/vws.     grid (512), 512 thr
// MODE 2: A = ows  [16384][512],  B = woutT -> out f32.    grid (256), 512 thr
// 8 waves as 2(M) x 4(N); per-wave output 128x64; acc[8][4] f32x4.
// LDS: 2 bufs x (A 256x64 + B 256x64) bf16 = 128 KiB. Half-tile = 128 rows.

// stage one half-tile (2 glds/thread). thread t: units t and t+512 of the
// half (unit = 16B). row r0=t>>3 (0..63; +64 for the second), uw=t&7;
// source pre-swizzled: global unit = uw ^ (r0&7)  ((r+64)&7 == r&7).
#define STG_AH(tile_, h_)                                                   \
  do {                                                                      \
    glds16(Ab + (size_t)((h_) * 128) * Ksz + (tile_) * 64,                  \
           &As[(tile_) & 1][(h_) * 8192 + t * 8]);                          \
    glds16(Ab + (size_t)((h_) * 128 + 64) * Ksz + (tile_) * 64,             \
           &As[(tile_) & 1][(h_) * 8192 + 4096 + t * 8]);                   \
  } while (0)
#define STG_BH(tile_, h_)                                                   \
  do {                                                                      \
    glds16(Bb + (size_t)((h_) * 128) * Ksz + (tile_) * 64,                  \
           &Bs[(tile_) & 1][(h_) * 8192 + t * 8]);                          \
    glds16(Bb + (size_t)((h_) * 128 + 64) * Ksz + (tile_) * 64,             \
           &Bs[(tile_) & 1][(h_) * 8192 + 4096 + t * 8]);                   \
  } while (0)

#define RD_A(lo_)                                                           \
  do {                                                                      \
    _Pragma("unroll")                                                       \
    for (int mf = (lo_); mf < (lo_) + 4; ++mf) {                            \
      af[mf][0] = *(const bf16x8*)&Ap[rA + mf * 1024 + s0];                 \
      af[mf][1] = *(const bf16x8*)&Ap[rA + mf * 1024 + s1];                 \
    }                                                                       \
  } while (0)
#define RD_B(lo_)                                                           \
  do {                                                                      \
    _Pragma("unroll")                                                       \
    for (int nf = (lo_); nf < (lo_) + 2; ++nf) {                            \
      bfr[nf][0] = *(const bf16x8*)&Bp[rB + nf * 1024 + s0];                \
      bfr[nf][1] = *(const bf16x8*)&Bp[rB + nf * 1024 + s1];                \
    }                                                                       \
  } while (0)

#define MFMA_Q(M0_, N0_)                                                    \
  do {                                                                      \
    _Pragma("unroll")                                                       \
    for (int mf = 0; mf < 4; ++mf)                                          \
      _Pragma("unroll")                                                     \
      for (int nf = 0; nf < 2; ++nf)                                        \
        _Pragma("unroll")                                                   \
        for (int kk = 0; kk < 2; ++kk)                                      \
          acc[(M0_) + mf][(N0_) + nf] =                                     \
              __builtin_amdgcn_mfma_f32_16x16x32_bf16(                      \
                  af[(M0_) + mf][kk], bfr[(N0_) + nf][kk],                  \
                  acc[(M0_) + mf][(N0_) + nf], 0, 0, 0);                    \
  } while (0)

#define PH_MID                                                              \
  SB0;                                                                      \
  __builtin_amdgcn_s_barrier();                                             \
  asm volatile("s_waitcnt lgkmcnt(0)");                                     \
  SB0;                                                                      \
  __builtin_amdgcn_s_setprio(1)
#define PH_END                                                              \
  __builtin_amdgcn_s_setprio(0);                                            \
  SB0;                                                                      \
  __builtin_amdgcn_s_barrier();                                             \
  SB0

template <int MODE>
__global__ __launch_bounds__(512, 2) void gemm256(const short* __restrict__ A,
                                                  const short* __restrict__ BT,
                                                  const float* __restrict__ bias,
                                                  void* __restrict__ C1v,
                                                  short* __restrict__ C2) {
  constexpr int Ksz = (MODE == 2) ? 512 : 1024;
  constexpr int NT = Ksz / 64;               // 16 (MODE1) / 8 (MODE2)
  __shared__ short As[2][16384];             // 2 bufs x 256 rows x 64 k
  __shared__ short Bs[2][16384];

  // chunked XCD swizzle (nwg % 8 == 0) + bn-fastest for A-panel L2 reuse
  const int nwg = gridDim.x;
  const int g = blockIdx.x;
  const int wg = (g & 7) * (nwg >> 3) + (g >> 3);
  const int bm = wg >> 2, bn = wg & 3;       // N = 1024 -> 4 col-tiles

  const int t = threadIdx.x;
  const int wid = t >> 6, lane = t & 63, qd = lane >> 4, ln = lane & 15;
  const int wm = wid >> 2, wn = wid & 3;

  const f32x4 zf = {0.f, 0.f, 0.f, 0.f};
  f32x4 acc[8][4];
#pragma unroll
  for (int mf = 0; mf < 8; ++mf)
#pragma unroll
    for (int nf = 0; nf < 4; ++nf) acc[mf][nf] = zf;

  // staging source (pre-swizzled)
  const int r0 = t >> 3, uw = t & 7;
  const int uu = uw ^ (r0 & 7);
  const short* Ab = A + ((size_t)bm * 256 + r0) * Ksz + uu * 8;
  const short* Bb = BT + ((size_t)bn * 256 + r0) * Ksz + uu * 8;

  // fragment-read offsets (shorts). row&7 == ln&7 for all frag rows.
  const int rA = (wm * 128 + ln) * 64;
  const int rB = (wn * 64 + ln) * 64;
  const int s0 = (qd ^ (ln & 7)) * 8;        // kk=0 swizzled unit
  const int s1 = ((4 + qd) ^ (ln & 7)) * 8;  // kk=1

  bf16x8 af[8][2], bfr[4][2];

  // ---- prologue: tile0 all 4 halves + hB(1); vmcnt(4) leaves hB(1) in flight
  STG_AH(0, 0); STG_AH(0, 1); STG_BH(0, 0); STG_BH(0, 1);
  STG_BH(1, 0); STG_BH(1, 1);
  SB0;
  asm volatile("s_waitcnt vmcnt(4)");
  __builtin_amdgcn_s_barrier();
  SB0;

  for (int kt = 0; kt < NT; ++kt) {
    const int cur = kt & 1;
    const short* Ap = &As[cur][0];
    const short* Bp = &Bs[cur][0];
    const bool s1ok = (kt + 1 < NT);
    const bool s2ok = (kt + 2 < NT);
    // ---- phase 1: reads 12; stage hA0(kt+1) -> buf^1; MFMA q(m0-3,n0-1)
    RD_A(0); RD_B(0);
    if (s1ok) STG_AH(kt + 1, 0);
    asm volatile("s_waitcnt lgkmcnt(8)");
    PH_MID;
    MFMA_Q(0, 0);
    PH_END;
    // ---- phase 2: reads 4; stage hA1(kt+1) -> buf^1; MFMA q(m0-3,n2-3)
    RD_B(2);
    if (s1ok) STG_AH(kt + 1, 1);
    PH_MID;
    MFMA_Q(0, 2);
    PH_END;
    // ---- phase 3: reads 8; stage hB0(kt+2) -> buf (B reads retired @ph2)
    RD_A(4);
    if (s2ok) STG_BH(kt + 2, 0);
    PH_MID;
    MFMA_Q(4, 0);
    PH_END;
    // ---- phase 4: stage hB1(kt+2); counted vmcnt; MFMA q(m4-7,n2-3)
    if (s2ok) STG_BH(kt + 2, 1);
    SB0;
    if (s2ok)      { asm volatile("s_waitcnt vmcnt(4)"); }   // hA(kt+1) landed
    else if (s1ok) { asm volatile("s_waitcnt vmcnt(0)"); }   // tail drain
    __builtin_amdgcn_s_barrier();
    SB0;
    __builtin_amdgcn_s_setprio(1);
    MFMA_Q(4, 2);
    PH_END;
  }

  // epilogue: C/D layout col=lane&15, row=(lane>>4)*4+reg
#pragma unroll
  for (int mf = 0; mf < 8; ++mf) {
    const int rbase = bm * 256 + wm * 128 + mf * 16 + qd * 4;
#pragma unroll
    for (int nf = 0; nf < 4; ++nf) {
      const int cc = bn * 256 + wn * 64 + nf * 16 + ln;
      float bia = 0.f;
      if constexpr (MODE == 2) bia = bias[cc];
#pragma unroll
      for (int rr = 0; rr < 4; ++rr) {
        const int rg = rbase + rr;
        const float v = acc[mf][nf][rr];
        if constexpr (MODE == 1) {
          int b = rg >> 13, j = rg & 8191;   // j = padded ctx row
          int nch = j >> 7, jc = j & 127;
          int d = cc & 63;
          if (cc < 512) {
            int h = cc >> 6;
            ((short*)C1v)[(((size_t)(b * 8 + h) * 64 + nch) * 128 + jc) * 64 + d] = f2bf(v);
          } else {
            int h = (cc - 512) >> 6;
            C2[(((size_t)(b * 8 + h) * 64 + nch) * 128 + jc) * 64 + d] = f2bf(v);
          }
        } else {
          int b = rg >> 12, i = rg & 4095;
          ((float*)C1v)[((size_t)b * 4097 + 1 + i) * 1024 + cc] = v + bia;
        }
      }
    }
  }
}

#undef STG_AH
#undef STG_BH
#undef RD_A
#undef RD_B
#undef MFMA_Q
#undef PH_MID
#undef PH_END

// ---------------- FAST GEMM: 128x128 tile, global_load_lds staging ----------
// MODE 0 only now: A = seqb, B = wqT, C -> qws bf16 (scaled 0.125). grid (128,4)
template <int MODE>
__global__ __launch_bounds__(256, 2) void gemm_fast(const short* __restrict__ A,
                                                    const short* __restrict__ BT,
                                                    const float* __restrict__ bias,
                                                    void* __restrict__ C1v,
                                                    short* __restrict__ C2) {
  constexpr int Ksz = (MODE == 2) ? 512 : 1024;
  __shared__ short As[128 * 32];   // unpadded: required by global_load_lds layout
  __shared__ short Bs[128 * 32];
  const int t = threadIdx.x;
  const int bm = blockIdx.x, bn = blockIdx.y;
  const int wid = t >> 6, lane = t & 63, qd = lane >> 4, ln = lane & 15;
  const int wm = wid >> 1, wn = wid & 1;

  const f32x4 zf = {0.f, 0.f, 0.f, 0.f};
  f32x4 acc[4][4];
#pragma unroll
  for (int it = 0; it < 4; ++it)
#pragma unroll
    for (int jt = 0; jt < 4; ++jt) acc[it][jt] = zf;

  const int srow = wid * 16 + (lane >> 2);         // 0..63
  const int scol = (lane & 3) * 8;                 // shorts
  const short* aA0 = A + ((size_t)bm * 128 + srow) * Ksz + scol;
  const short* aA1 = aA0 + (size_t)64 * Ksz;
  const short* aB0 = BT + ((size_t)bn * 128 + srow) * Ksz + scol;
  const short* aB1 = aB0 + (size_t)64 * Ksz;
  short* lA0 = &As[srow * 32 + scol];
  short* lA1 = &As[(64 + srow) * 32 + scol];
  short* lB0 = &Bs[srow * 32 + scol];
  short* lB1 = &Bs[(64 + srow) * 32 + scol];

  for (int kt = 0; kt < Ksz / 32; ++kt) {
    const int ko = kt * 32;
    glds16(aA0 + ko, lA0);
    glds16(aA1 + ko, lA1);
    glds16(aB0 + ko, lB0);
    glds16(aB1 + ko, lB1);
    __syncthreads();
    bf16x8 af[4], bfv[4];
#pragma unroll
    for (int it = 0; it < 4; ++it)
      af[it] = *(const bf16x8*)&As[(wm * 64 + it * 16 + ln) * 32 + qd * 8];
#pragma unroll
    for (int jt = 0; jt < 4; ++jt)
      bfv[jt] = *(const bf16x8*)&Bs[(wn * 64 + jt * 16 + ln) * 32 + qd * 8];
#pragma unroll
    for (int it = 0; it < 4; ++it)
#pragma unroll
      for (int jt = 0; jt < 4; ++jt)
        acc[it][jt] = __builtin_amdgcn_mfma_f32_16x16x32_bf16(af[it], bfv[jt], acc[it][jt], 0, 0, 0);
    __syncthreads();
  }

#pragma unroll
  for (int it = 0; it < 4; ++it) {
    const int rbase = bm * 128 + wm * 64 + it * 16 + qd * 4;
#pragma unroll
    for (int jt = 0; jt < 4; ++jt) {
      const int cc = bn * 128 + wn * 64 + jt * 16 + ln;
      float bia = 0.f;
      if constexpr (MODE == 2) bia = bias[cc];
#pragma unroll
      for (int rr = 0; rr < 4; ++rr) {
        const int rg = rbase + rr;
        const float v = acc[it][jt][rr];
        if constexpr (MODE == 0) {
          int b = rg >> 12, i = rg & 4095;
          int nch = i >> 6, ic = i & 63;
          int h = cc >> 6, d = cc & 63;
          ((short*)C1v)[(((size_t)(b * 8 + h) * 64 + nch) * 64 + ic) * 64 + d] = f2bf(v * 0.125f);
        } else if constexpr (MODE == 1) {
          int b = rg >> 13, j = rg & 8191;
          int nch = j >> 7, jc = j & 127;
          int d = cc & 63;
          if (cc < 512) {
            int h = cc >> 6;
            ((short*)C1v)[(((size_t)(b * 8 + h) * 64 + nch) * 128 + jc) * 64 + d] = f2bf(v);
          } else {
            int h = (cc - 512) >> 6;
            C2[(((size_t)(b * 8 + h) * 64 + nch) * 128 + jc) * 64 + d] = f2bf(v);
          }
        } else {
          int b = rg >> 12, i = rg & 4095;
          ((float*)C1v)[((size_t)b * 4097 + 1 + i) * 1024 + cc] = v + bia;
        }
      }
    }
  }
}

// ---------------- FALLBACK GEMM (round-3, f32 A staging) --------------------
template <int MODE>
__global__ __launch_bounds__(256, 2) void gemm_k(const void* __restrict__ Av,
                                                 const short* __restrict__ BT,
                                                 const float* __restrict__ bias,
                                                 void* __restrict__ C1v,
                                                 short* __restrict__ C2) {
  constexpr int Ksz = (MODE == 2) ? 512 : 1024;
  __shared__ short As[128 * 40];
  __shared__ short Bs[128 * 40];
  const int t = threadIdx.x;
  const int bm = blockIdx.x, bn = blockIdx.y;
  const int wid = t >> 6, lane = t & 63, qd = lane >> 4, ln = lane & 15;
  const int wm = wid >> 1, wn = wid & 1;

  const f32x4 zf = {0.f, 0.f, 0.f, 0.f};
  f32x4 acc[4][4];
#pragma unroll
  for (int it = 0; it < 4; ++it)
#pragma unroll
    for (int jt = 0; jt < 4; ++jt) acc[it][jt] = zf;

  const int arow = t >> 1;
  const int koff = (t & 1) * 16;
  const float* asrcF = nullptr;
  const short* asrcB = nullptr;
  bool avalid = true;
  {
    int gr = bm * 128 + arow;
    if constexpr (MODE == 0) {
      int b = gr >> 12, i = gr & 4095;
      asrcF = (const float*)Av + ((size_t)b * 4097 + 1 + i) * 1024;
    } else if constexpr (MODE == 1) {
      int b = gr >> 13, j = gr & 8191;
      avalid = (j >= 127);
      asrcF = (const float*)Av + ((size_t)b * 8065 + (j - 127)) * 1024;
    } else {
      asrcB = (const short*)Av + (size_t)gr * 512;
    }
  }
  const short* bsrc = BT + (size_t)(bn * 128 + arow) * Ksz;

  for (int kt = 0; kt < Ksz / 32; ++kt) {
    const int k0 = kt * 32 + koff;
    bf16x8 a0, a1;
    if constexpr (MODE == 2) {
      a0 = *(const bf16x8*)(asrcB + k0);
      a1 = *(const bf16x8*)(asrcB + k0 + 8);
    } else {
      f32x4 f0 = zf, f1 = zf, f2 = zf, f3 = zf;
      if (avalid) {
        f0 = *(const f32x4*)(asrcF + k0);
        f1 = *(const f32x4*)(asrcF + k0 + 4);
        f2 = *(const f32x4*)(asrcF + k0 + 8);
        f3 = *(const f32x4*)(asrcF + k0 + 12);
      }
#pragma unroll
      for (int i = 0; i < 4; ++i) {
        a0[i]     = f2bf_r(f0[i]);
        a0[i + 4] = f2bf_r(f1[i]);
        a1[i]     = f2bf_r(f2[i]);
        a1[i + 4] = f2bf_r(f3[i]);
      }
    }
    bf16x8 b0 = *(const bf16x8*)(bsrc + k0);
    bf16x8 b1 = *(const bf16x8*)(bsrc + k0 + 8);
    *(bf16x8*)&As[arow * 40 + koff] = a0;
    *(bf16x8*)&As[arow * 40 + koff + 8] = a1;
    *(bf16x8*)&Bs[arow * 40 + koff] = b0;
    *(bf16x8*)&Bs[arow * 40 + koff + 8] = b1;
    __syncthreads();
    bf16x8 af[4], bfv[4];
#pragma unroll
    for (int it = 0; it < 4; ++it)
      af[it] = *(const bf16x8*)&As[(wm * 64 + it * 16 + ln) * 40 + qd * 8];
#pragma unroll
    for (int jt = 0; jt < 4; ++jt)
      bfv[jt] = *(const bf16x8*)&Bs[(wn * 64 + jt * 16 + ln) * 40 + qd * 8];
#pragma unroll
    for (int it = 0; it < 4; ++it)
#pragma unroll
      for (int jt = 0; jt < 4; ++jt)
        acc[it][jt] = __builtin_amdgcn_mfma_f32_16x16x32_bf16(af[it], bfv[jt], acc[it][jt], 0, 0, 0);
    __syncthreads();
  }

#pragma unroll
  for (int it = 0; it < 4; ++it) {
    const int rbase = bm * 128 + wm * 64 + it * 16 + qd * 4;
#pragma unroll
    for (int jt = 0; jt < 4; ++jt) {
      const int cc = bn * 128 + wn * 64 + jt * 16 + ln;
      float bia = 0.f;
      if constexpr (MODE == 2) bia = bias[cc];
#pragma unroll
      for (int rr = 0; rr < 4; ++rr) {
        const int rg = rbase + rr;
        const float v = acc[it][jt][rr];
        if constexpr (MODE == 0) {
          int b = rg >> 12, i = rg & 4095;
          int nch = i >> 6, ic = i & 63;
          int h = cc >> 6, d = cc & 63;
          ((short*)C1v)[(((size_t)(b * 8 + h) * 64 + nch) * 64 + ic) * 64 + d] = f2bf(v * 0.125f);
        } else if constexpr (MODE == 1) {
          int b = rg >> 13, j = rg & 8191;
          int nch = j >> 7, jc = j & 127;
          int d = cc & 63;
          if (cc < 512) {
            int h = cc >> 6;
            ((short*)C1v)[(((size_t)(b * 8 + h) * 64 + nch) * 128 + jc) * 64 + d] = f2bf(v);
          } else {
            int h = (cc - 512) >> 6;
            C2[(((size_t)(b * 8 + h) * 64 + nch) * 128 + jc) * 64 + d] = f2bf(v);
          }
        } else {
          int b = rg >> 12, i = rg & 4095;
          ((float*)C1v)[((size_t)b * 4097 + 1 + i) * 1024 + cc] = v + bia;
        }
      }
    }
  }
}

// ---------------- fused attention (sim, softmax, talking-heads, PV) ---------
__global__ __launch_bounds__(512, 2) void attn_kernel(
    const short* __restrict__ qws, const short* __restrict__ kws,
    const short* __restrict__ vws, const float* __restrict__ null_k,
    const float* __restrict__ null_v, const float* __restrict__ W_th,
    const float* __restrict__ b_th, short* __restrict__ ows) {
  __shared__ short P[8 * 16 * 152];

  const int blk = blockIdx.x;
  const int b = blk >> 8;
  const int rem = blk & 255;
  const int nch = rem >> 2;
  const int qh = rem & 3;
  const int tid = threadIdx.x;
  const int wid = tid >> 6;
  const int lane = tid & 63;
  const int qd = lane >> 4, ln = lane & 15;

  const bf16x8 z8 = {0, 0, 0, 0, 0, 0, 0, 0};
  const f32x4 zf = {0.f, 0.f, 0.f, 0.f};

  const short* qb = qws + ((size_t)(b * 8 + wid) * 64 + nch) * 64 * 64;
  const short* kb = kws + ((size_t)(b * 8 + wid) * 64 + nch) * 128 * 64;

  bf16x8 qf[2];
#pragma unroll
  for (int kk = 0; kk < 2; ++kk)
    qf[kk] = *(const bf16x8*)(qb + (qh * 16 + ln) * 64 + kk * 32 + qd * 8);

  f32x4 acc[9];
#pragma unroll
  for (int jt = 0; jt < 9; ++jt) acc[jt] = zf;

#pragma unroll
  for (int jt = 0; jt < 8; ++jt) {
#pragma unroll
    for (int kk = 0; kk < 2; ++kk) {
      bf16x8 bfr = *(const bf16x8*)(kb + (jt * 16 + ln) * 64 + kk * 32 + qd * 8);
      acc[jt] = __builtin_amdgcn_mfma_f32_16x16x32_bf16(qf[kk], bfr, acc[jt], 0, 0, 0);
    }
  }
  {
#pragma unroll
    for (int kk = 0; kk < 2; ++kk) {
      bf16x8 nk = z8;
      if (ln == 0) {
#pragma unroll
        for (int j = 0; j < 8; ++j)
          nk[j] = f2bf(null_k[wid * 64 + kk * 32 + qd * 8 + j]);
      }
      acc[8] = __builtin_amdgcn_mfma_f32_16x16x32_bf16(qf[kk], nk, acc[8], 0, 0, 0);
    }
  }

#pragma unroll
  for (int rr = 0; rr < 4; ++rr) {
    float v[9];
    float m = -3.0e38f;
#pragma unroll
    for (int jt = 0; jt < 9; ++jt) {
      float x = acc[jt][rr];
      if (jt == 8 && ln != 0) x = -3.0e38f;
      v[jt] = x;
      m = fmaxf(m, x);
    }
#pragma unroll
    for (int s = 1; s < 16; s <<= 1) m = fmaxf(m, __shfl_xor(m, s, 64));
    float sum = 0.f;
#pragma unroll
    for (int jt = 0; jt < 9; ++jt) {
      float e = (jt == 8 && ln != 0) ? 0.f : exp2f((v[jt] - m) * 1.44269504f);
      v[jt] = e;
      sum += e;
    }
#pragma unroll
    for (int s = 1; s < 16; s <<= 1) sum += __shfl_xor(sum, s, 64);
    const float inv = 1.0f / sum;
    const int row = qd * 4 + rr;
#pragma unroll
    for (int jt = 0; jt < 9; ++jt)
      P[(wid * 16 + row) * 152 + jt * 16 + ln] = f2bf(v[jt] * inv);
  }
  __syncthreads();

  {
    float w[64];
#pragma unroll
    for (int i = 0; i < 64; ++i) {
      union { float f; int i; } u;
      u.f = W_th[i];
      u.i = __builtin_amdgcn_readfirstlane(u.i);
      w[i] = u.f;
    }
    float bt[8];
#pragma unroll
    for (int g = 0; g < 8; ++g) {
      union { float f; int i; } u;
      u.f = b_th[g];
      u.i = __builtin_amdgcn_readfirstlane(u.i);
      bt[g] = u.f;
    }
    const int r = tid >> 5;
    const int c0 = (tid & 31) * 5;
    for (int c = c0; c < c0 + 5 && c < 129; ++c) {
      float v[8];
#pragma unroll
      for (int h = 0; h < 8; ++h) v[h] = bf2f(P[(h * 16 + r) * 152 + c]);
      float o[8];
#pragma unroll
      for (int g = 0; g < 8; ++g) {
        float s = bt[g];
#pragma unroll
        for (int h = 0; h < 8; ++h) s += w[g * 8 + h] * v[h];
        o[g] = s;
      }
#pragma unroll
      for (int g = 0; g < 8; ++g) P[(g * 16 + r) * 152 + c] = f2bf(o[g]);
    }
  }
  __syncthreads();

  const short* vb = vws + ((size_t)(b * 8 + wid) * 64 + nch) * 128 * 64;
  bf16x8 vf[4][4];
#pragma unroll
  for (int kk = 0; kk < 4; ++kk)
#pragma unroll
    for (int dt = 0; dt < 4; ++dt) {
      bf16x8 tmp;
#pragma unroll
      for (int jj = 0; jj < 8; ++jj)
        tmp[jj] = vb[(kk * 32 + qd * 8 + jj) * 64 + dt * 16 + ln];
      vf[kk][dt] = tmp;
    }

  f32x4 oacc[4];
#pragma unroll
  for (int dt = 0; dt < 4; ++dt) oacc[dt] = zf;

#pragma unroll
  for (int kk = 0; kk < 4; ++kk) {
    bf16x8 af = *(const bf16x8*)&P[(wid * 16 + ln) * 152 + kk * 32 + qd * 8];
#pragma unroll
    for (int dt = 0; dt < 4; ++dt)
      oacc[dt] = __builtin_amdgcn_mfma_f32_16x16x32_bf16(af, vf[kk][dt], oacc[dt], 0, 0, 0);
  }
  {
    float nv[4];
#pragma unroll
    for (int dt = 0; dt < 4; ++dt) nv[dt] = null_v[wid * 64 + dt * 16 + ln];
#pragma unroll
    for (int rr = 0; rr < 4; ++rr) {
      float p = bf2f(P[(wid * 16 + qd * 4 + rr) * 152 + 128]);
#pragma unroll
      for (int dt = 0; dt < 4; ++dt) oacc[dt][rr] += p * nv[dt];
    }
  }
  const size_t rowbase = (size_t)b * 4096 + nch * 64 + qh * 16;
#pragma unroll
  for (int dt = 0; dt < 4; ++dt)
#pragma unroll
    for (int rr = 0; rr < 4; ++rr)
      ows[(rowbase + qd * 4 + rr) * 512 + wid * 64 + dt * 16 + ln] = f2bf(oacc[dt][rr]);
}

// ---------------------------------------------------------------------------
extern "C" void kernel_launch(void* const* d_in, const int* in_sizes, int n_in,
                              void* d_out, int out_size, void* d_ws, size_t ws_size,
                              hipStream_t stream) {
  const float* seq   = (const float*)d_in[0];
  const float* ctx   = (const float*)d_in[1];
  const float* Wq    = (const float*)d_in[2];
  const float* Wkv   = (const float*)d_in[3];
  const float* Wout  = (const float*)d_in[4];
  const float* b_out = (const float*)d_in[5];
  const float* nullk = (const float*)d_in[6];
  const float* nullv = (const float*)d_in[7];
  const float* W_th  = (const float*)d_in[8];
  const float* b_th  = (const float*)d_in[9];

  char* ws = (char*)d_ws;
  float* out = (float*)d_out;
  const bool fast = ws_size >= 188743680ull;

  if (fast) {
    short* seqb  = (short*)(ws);
    short* ows   = (short*)(ws);                 // reuses seqb after Q GEMM
    short* ctxb  = (short*)(ws + 33554432);
    short* qws   = (short*)(ws + 100663296);
    short* kws   = (short*)(ws + 117440512);
    short* vws   = (short*)(ws + 150994944);
    short* wqT   = (short*)(ws + 184549376);
    short* wkvT  = (short*)(ws + 185597952);
    short* woutT = (short*)(ws + 187695104);

    hipLaunchKernelGGL(transpose_w, dim3(8192), dim3(256), 0, stream,
                       Wq, Wkv, Wout, wqT, wkvT, woutT);
    hipLaunchKernelGGL(conv_seq, dim3(8192), dim3(256), 0, stream, seq, seqb);
    hipLaunchKernelGGL(conv_ctx, dim3(16384), dim3(256), 0, stream, ctx, ctxb);
    hipLaunchKernelGGL((gemm_fast<0>), dim3(128, 4), dim3(256), 0, stream,
                       seqb, wqT, (const float*)nullptr, (void*)qws, (short*)nullptr);
    hipLaunchKernelGGL((gemm256<1>), dim3(512), dim3(512), 0, stream,
                       ctxb, wkvT, (const float*)nullptr, (void*)kws, vws);
    hipLaunchKernelGGL(attn_kernel, dim3(1024), dim3(512), 0, stream,
                       qws, kws, vws, nullk, nullv, W_th, b_th, ows);
    hipLaunchKernelGGL(zero_rows, dim3(16), dim3(256), 0, stream, out);
    hipLaunchKernelGGL((gemm256<2>), dim3(256), dim3(512), 0, stream,
                       ows, woutT, b_out, (void*)out, (short*)nullptr);
  } else {
    short* qws   = (short*)(ws);
    short* kws   = (short*)(ws + 16777216);
    short* vws   = (short*)(ws + 50331648);
    short* ows   = (short*)(ws + 83886080);
    short* wqT   = (short*)(ws + 100663296);
    short* wkvT  = (short*)(ws + 101711872);
    short* woutT = (short*)(ws + 103809024);

    hipLaunchKernelGGL(transpose_w, dim3(8192), dim3(256), 0, stream,
                       Wq, Wkv, Wout, wqT, wkvT, woutT);
    hipLaunchKernelGGL((gemm_k<0>), dim3(128, 4), dim3(256), 0, stream,
                       (const void*)seq, wqT, (const float*)nullptr, (void*)qws, (short*)nullptr);
    hipLaunchKernelGGL((gemm_k<1>), dim3(256, 8), dim3(256), 0, stream,
                       (const void*)ctx, wkvT, (const float*)nullptr, (void*)kws, vws);
    hipLaunchKernelGGL(attn_kernel, dim3(1024), dim3(512), 0, stream,
                       qws, kws, vws, nullk, nullv, W_th, b_th, ows);
    hipLaunchKernelGGL(zero_rows, dim3(16), dim3(256), 0, stream, out);
    hipLaunchKernelGGL((gemm_k<2>), dim3(128, 8), dim3(256), 0, stream,
                       (const void*)ows, woutT, b_out, (void*)out, (short*)nullptr);
  }
}

// Round 4
// 468.530 us; speedup vs baseline: 1.0570x; 1.0570x over previous
//
#include <hip/hip_runtime.h>

// ---------------------------------------------------------------------------
// CrossModalityCrossAttention on MI355X (gfx950). I/O: float32. Internal: bf16.
// B=4 S=4097 L=8065 D=1024 H=8 DH=64 CHUNK=64 CCS=128 n=64 chunks.
//
// R4: attn_kernel restructured for 4x K/V reuse. Old grid (b,nch,qh)=1024
// blocks re-read each (b,nch)'s K/V tiles 4x (FETCH 140 MB vs 84 ideal).
// New grid (b,nch)=256 blocks, wave=head, 4 q-groups looped in-block; K/V/
// null fragments register-resident across groups (~220 VGPR, cap 256).
// gemm256 (R3 m201-style 8-phase), gemm_fast, conv, fallback unchanged.
// ---------------------------------------------------------------------------

typedef __attribute__((ext_vector_type(8))) short bf16x8;
typedef __attribute__((ext_vector_type(4))) float f32x4;

__device__ __forceinline__ short f2bf(float x) {        // RNE (epilogues, weights)
  union { float f; unsigned u; } v; v.f = x;
  unsigned r = v.u + 0x7FFFu + ((v.u >> 16) & 1u);
  return (short)(r >> 16);
}
__device__ __forceinline__ short f2bf_r(float x) {      // round-half-up (staging)
  union { float f; unsigned u; } v; v.f = x;
  return (short)((v.u + 0x8000u) >> 16);
}
__device__ __forceinline__ float bf2f(short s) {
  union { unsigned u; float f; } v;
  v.u = ((unsigned)(unsigned short)s) << 16;
  return v.f;
}
__device__ __forceinline__ void glds16(const short* g, short* l) {
  __builtin_amdgcn_global_load_lds(
      (const __attribute__((address_space(1))) void*)g,
      (__attribute__((address_space(3))) void*)l, 16, 0, 0);
}

#define SB0 __builtin_amdgcn_sched_barrier(0)

// ---------------- weight transpose (f32 [k][n] -> bf16 [n][k]) --------------
__global__ void transpose_w(const float* __restrict__ Wq, const float* __restrict__ Wkv,
                            const float* __restrict__ Wout,
                            short* __restrict__ wqT, short* __restrict__ wkvT,
                            short* __restrict__ woutT) {
  int idx = blockIdx.x * 256 + threadIdx.x;
  if (idx < 524288) {                       // Wq (1024 x 512)
    int d = idx >> 9, e = idx & 511;
    wqT[e * 1024 + d] = f2bf(Wq[idx]);
  } else if (idx < 1572864) {               // Wkv (1024 x 1024)
    int i = idx - 524288;
    int d = i >> 10, e = i & 1023;
    wkvT[e * 1024 + d] = f2bf(Wkv[i]);
  } else if (idx < 2097152) {               // Wout (512 x 1024)
    int i = idx - 1572864;
    int k = i >> 10, e = i & 1023;
    woutT[e * 512 + k] = f2bf(Wout[i]);
  }
}

// ---------------- f32 -> bf16 conversion passes (fast path) -----------------
__global__ void conv_seq(const float* __restrict__ seq, short* __restrict__ seqb) {
  size_t e = ((size_t)blockIdx.x * 256 + threadIdx.x) * 8;   // 16,777,216 elems
  int b = (int)(e >> 22);
  int i = (int)((e >> 10) & 4095);
  int k = (int)(e & 1023);
  const float* src = seq + ((size_t)b * 4097 + 1 + i) * 1024 + k;
  f32x4 f0 = *(const f32x4*)src;
  f32x4 f1 = *(const f32x4*)(src + 4);
  bf16x8 o;
#pragma unroll
  for (int j = 0; j < 4; ++j) { o[j] = f2bf_r(f0[j]); o[j + 4] = f2bf_r(f1[j]); }
  *(bf16x8*)(seqb + e) = o;
}

__global__ void conv_ctx(const float* __restrict__ ctx, short* __restrict__ ctxb) {
  size_t e = ((size_t)blockIdx.x * 256 + threadIdx.x) * 8;   // 33,554,432 elems
  int b = (int)(e >> 23);
  int r = (int)((e >> 10) & 8191);
  int k = (int)(e & 1023);
  bf16x8 o = {0, 0, 0, 0, 0, 0, 0, 0};
  if (r >= 127) {                            // rows 0..126 are the left pad
    const float* src = ctx + ((size_t)b * 8065 + (r - 127)) * 1024 + k;
    f32x4 f0 = *(const f32x4*)src;
    f32x4 f1 = *(const f32x4*)(src + 4);
#pragma unroll
    for (int j = 0; j < 4; ++j) { o[j] = f2bf_r(f0[j]); o[j + 4] = f2bf_r(f1[j]); }
  }
  *(bf16x8*)(ctxb + e) = o;
}

// ---------------- zero the (b, 0, :) output rows (f32) ----------------------
__global__ void zero_rows(float* __restrict__ out) {
  int idx = blockIdx.x * 256 + threadIdx.x;   // 4096 total
  if (idx < 4096) out[(size_t)(idx >> 10) * (4097u * 1024u) + (idx & 1023)] = 0.f;
}

// ---------------- 256x256 m201-style 8-phase GEMM ---------------------------
// MODE 1: A = ctxb [32768][1024], B = wkvT -> kws/vws.     grid (512), 512 thr
// MODE 2: A = ows  [16384][512],  B = woutT -> out f32.    grid (256), 512 thr
// 8 waves as 2(M) x 4(N); per-wave output 128x64; acc[8][4] f32x4.
// LDS: 2 bufs x (A 256x64 + B 256x64) bf16 = 128 KiB. Half-tile = 128 rows.

#define STG_AH(tile_, h_)                                                   \
  do {                                                                      \
    glds16(Ab + (size_t)((h_) * 128) * Ksz + (tile_) * 64,                  \
           &As[(tile_) & 1][(h_) * 8192 + t * 8]);                          \
    glds16(Ab + (size_t)((h_) * 128 + 64) * Ksz + (tile_) * 64,             \
           &As[(tile_) & 1][(h_) * 8192 + 4096 + t * 8]);                   \
  } while (0)
#define STG_BH(tile_, h_)                                                   \
  do {                                                                      \
    glds16(Bb + (size_t)((h_) * 128) * Ksz + (tile_) * 64,                  \
           &Bs[(tile_) & 1][(h_) * 8192 + t * 8]);                          \
    glds16(Bb + (size_t)((h_) * 128 + 64) * Ksz + (tile_) * 64,             \
           &Bs[(tile_) & 1][(h_) * 8192 + 4096 + t * 8]);                   \
  } while (0)

#define RD_A(lo_)                                                           \
  do {                                                                      \
    _Pragma("unroll")                                                       \
    for (int mf = (lo_); mf < (lo_) + 4; ++mf) {                            \
      af[mf][0] = *(const bf16x8*)&Ap[rA + mf * 1024 + s0];                 \
      af[mf][1] = *(const bf16x8*)&Ap[rA + mf * 1024 + s1];                 \
    }                                                                       \
  } while (0)
#define RD_B(lo_)                                                           \
  do {                                                                      \
    _Pragma("unroll")                                                       \
    for (int nf = (lo_); nf < (lo_) + 2; ++nf) {                            \
      bfr[nf][0] = *(const bf16x8*)&Bp[rB + nf * 1024 + s0];                \
      bfr[nf][1] = *(const bf16x8*)&Bp[rB + nf * 1024 + s1];                \
    }                                                                       \
  } while (0)

#define MFMA_Q(M0_, N0_)                                                    \
  do {                                                                      \
    _Pragma("unroll")                                                       \
    for (int mf = 0; mf < 4; ++mf)                                          \
      _Pragma("unroll")                                                     \
      for (int nf = 0; nf < 2; ++nf)                                        \
        _Pragma("unroll")                                                   \
        for (int kk = 0; kk < 2; ++kk)                                      \
          acc[(M0_) + mf][(N0_) + nf] =                                     \
              __builtin_amdgcn_mfma_f32_16x16x32_bf16(                      \
                  af[(M0_) + mf][kk], bfr[(N0_) + nf][kk],                  \
                  acc[(M0_) + mf][(N0_) + nf], 0, 0, 0);                    \
  } while (0)

#define PH_MID                                                              \
  SB0;                                                                      \
  __builtin_amdgcn_s_barrier();                                             \
  asm volatile("s_waitcnt lgkmcnt(0)");                                     \
  SB0;                                                                      \
  __builtin_amdgcn_s_setprio(1)
#define PH_END                                                              \
  __builtin_amdgcn_s_setprio(0);                                            \
  SB0;                                                                      \
  __builtin_amdgcn_s_barrier();                                             \
  SB0

template <int MODE>
__global__ __launch_bounds__(512, 2) void gemm256(const short* __restrict__ A,
                                                  const short* __restrict__ BT,
                                                  const float* __restrict__ bias,
                                                  void* __restrict__ C1v,
                                                  short* __restrict__ C2) {
  constexpr int Ksz = (MODE == 2) ? 512 : 1024;
  constexpr int NT = Ksz / 64;               // 16 (MODE1) / 8 (MODE2)
  __shared__ short As[2][16384];             // 2 bufs x 256 rows x 64 k
  __shared__ short Bs[2][16384];

  // chunked XCD swizzle (nwg % 8 == 0) + bn-fastest for A-panel L2 reuse
  const int nwg = gridDim.x;
  const int g = blockIdx.x;
  const int wg = (g & 7) * (nwg >> 3) + (g >> 3);
  const int bm = wg >> 2, bn = wg & 3;       // N = 1024 -> 4 col-tiles

  const int t = threadIdx.x;
  const int wid = t >> 6, lane = t & 63, qd = lane >> 4, ln = lane & 15;
  const int wm = wid >> 2, wn = wid & 3;

  const f32x4 zf = {0.f, 0.f, 0.f, 0.f};
  f32x4 acc[8][4];
#pragma unroll
  for (int mf = 0; mf < 8; ++mf)
#pragma unroll
    for (int nf = 0; nf < 4; ++nf) acc[mf][nf] = zf;

  // staging source (pre-swizzled)
  const int r0 = t >> 3, uw = t & 7;
  const int uu = uw ^ (r0 & 7);
  const short* Ab = A + ((size_t)bm * 256 + r0) * Ksz + uu * 8;
  const short* Bb = BT + ((size_t)bn * 256 + r0) * Ksz + uu * 8;

  // fragment-read offsets (shorts). row&7 == ln&7 for all frag rows.
  const int rA = (wm * 128 + ln) * 64;
  const int rB = (wn * 64 + ln) * 64;
  const int s0 = (qd ^ (ln & 7)) * 8;        // kk=0 swizzled unit
  const int s1 = ((4 + qd) ^ (ln & 7)) * 8;  // kk=1

  bf16x8 af[8][2], bfr[4][2];

  // ---- prologue: tile0 all 4 halves + hB(1); vmcnt(4) leaves hB(1) in flight
  STG_AH(0, 0); STG_AH(0, 1); STG_BH(0, 0); STG_BH(0, 1);
  STG_BH(1, 0); STG_BH(1, 1);
  SB0;
  asm volatile("s_waitcnt vmcnt(4)");
  __builtin_amdgcn_s_barrier();
  SB0;

  for (int kt = 0; kt < NT; ++kt) {
    const int cur = kt & 1;
    const short* Ap = &As[cur][0];
    const short* Bp = &Bs[cur][0];
    const bool s1ok = (kt + 1 < NT);
    const bool s2ok = (kt + 2 < NT);
    // ---- phase 1: reads 12; stage hA0(kt+1) -> buf^1; MFMA q(m0-3,n0-1)
    RD_A(0); RD_B(0);
    if (s1ok) STG_AH(kt + 1, 0);
    asm volatile("s_waitcnt lgkmcnt(8)");
    PH_MID;
    MFMA_Q(0, 0);
    PH_END;
    // ---- phase 2: reads 4; stage hA1(kt+1) -> buf^1; MFMA q(m0-3,n2-3)
    RD_B(2);
    if (s1ok) STG_AH(kt + 1, 1);
    PH_MID;
    MFMA_Q(0, 2);
    PH_END;
    // ---- phase 3: reads 8; stage hB0(kt+2) -> buf (B reads retired @ph2)
    RD_A(4);
    if (s2ok) STG_BH(kt + 2, 0);
    PH_MID;
    MFMA_Q(4, 0);
    PH_END;
    // ---- phase 4: stage hB1(kt+2); counted vmcnt; MFMA q(m4-7,n2-3)
    if (s2ok) STG_BH(kt + 2, 1);
    SB0;
    if (s2ok)      { asm volatile("s_waitcnt vmcnt(4)"); }   // hA(kt+1) landed
    else if (s1ok) { asm volatile("s_waitcnt vmcnt(0)"); }   // tail drain
    __builtin_amdgcn_s_barrier();
    SB0;
    __builtin_amdgcn_s_setprio(1);
    MFMA_Q(4, 2);
    PH_END;
  }

  // epilogue: C/D layout col=lane&15, row=(lane>>4)*4+reg
#pragma unroll
  for (int mf = 0; mf < 8; ++mf) {
    const int rbase = bm * 256 + wm * 128 + mf * 16 + qd * 4;
#pragma unroll
    for (int nf = 0; nf < 4; ++nf) {
      const int cc = bn * 256 + wn * 64 + nf * 16 + ln;
      float bia = 0.f;
      if constexpr (MODE == 2) bia = bias[cc];
#pragma unroll
      for (int rr = 0; rr < 4; ++rr) {
        const int rg = rbase + rr;
        const float v = acc[mf][nf][rr];
        if constexpr (MODE == 1) {
          int b = rg >> 13, j = rg & 8191;   // j = padded ctx row
          int nch = j >> 7, jc = j & 127;
          int d = cc & 63;
          if (cc < 512) {
            int h = cc >> 6;
            ((short*)C1v)[(((size_t)(b * 8 + h) * 64 + nch) * 128 + jc) * 64 + d] = f2bf(v);
          } else {
            int h = (cc - 512) >> 6;
            C2[(((size_t)(b * 8 + h) * 64 + nch) * 128 + jc) * 64 + d] = f2bf(v);
          }
        } else {
          int b = rg >> 12, i = rg & 4095;
          ((float*)C1v)[((size_t)b * 4097 + 1 + i) * 1024 + cc] = v + bia;
        }
      }
    }
  }
}

#undef STG_AH
#undef STG_BH
#undef RD_A
#undef RD_B
#undef MFMA_Q
#undef PH_MID
#undef PH_END

// ---------------- FAST GEMM: 128x128 tile, global_load_lds staging ----------
// MODE 0 only now: A = seqb, B = wqT, C -> qws bf16 (scaled 0.125). grid (128,4)
template <int MODE>
__global__ __launch_bounds__(256, 2) void gemm_fast(const short* __restrict__ A,
                                                    const short* __restrict__ BT,
                                                    const float* __restrict__ bias,
                                                    void* __restrict__ C1v,
                                                    short* __restrict__ C2) {
  constexpr int Ksz = (MODE == 2) ? 512 : 1024;
  __shared__ short As[128 * 32];   // unpadded: required by global_load_lds layout
  __shared__ short Bs[128 * 32];
  const int t = threadIdx.x;
  const int bm = blockIdx.x, bn = blockIdx.y;
  const int wid = t >> 6, lane = t & 63, qd = lane >> 4, ln = lane & 15;
  const int wm = wid >> 1, wn = wid & 1;

  const f32x4 zf = {0.f, 0.f, 0.f, 0.f};
  f32x4 acc[4][4];
#pragma unroll
  for (int it = 0; it < 4; ++it)
#pragma unroll
    for (int jt = 0; jt < 4; ++jt) acc[it][jt] = zf;

  const int srow = wid * 16 + (lane >> 2);         // 0..63
  const int scol = (lane & 3) * 8;                 // shorts
  const short* aA0 = A + ((size_t)bm * 128 + srow) * Ksz + scol;
  const short* aA1 = aA0 + (size_t)64 * Ksz;
  const short* aB0 = BT + ((size_t)bn * 128 + srow) * Ksz + scol;
  const short* aB1 = aB0 + (size_t)64 * Ksz;
  short* lA0 = &As[srow * 32 + scol];
  short* lA1 = &As[(64 + srow) * 32 + scol];
  short* lB0 = &Bs[srow * 32 + scol];
  short* lB1 = &Bs[(64 + srow) * 32 + scol];

  for (int kt = 0; kt < Ksz / 32; ++kt) {
    const int ko = kt * 32;
    glds16(aA0 + ko, lA0);
    glds16(aA1 + ko, lA1);
    glds16(aB0 + ko, lB0);
    glds16(aB1 + ko, lB1);
    __syncthreads();
    bf16x8 af[4], bfv[4];
#pragma unroll
    for (int it = 0; it < 4; ++it)
      af[it] = *(const bf16x8*)&As[(wm * 64 + it * 16 + ln) * 32 + qd * 8];
#pragma unroll
    for (int jt = 0; jt < 4; ++jt)
      bfv[jt] = *(const bf16x8*)&Bs[(wn * 64 + jt * 16 + ln) * 32 + qd * 8];
#pragma unroll
    for (int it = 0; it < 4; ++it)
#pragma unroll
      for (int jt = 0; jt < 4; ++jt)
        acc[it][jt] = __builtin_amdgcn_mfma_f32_16x16x32_bf16(af[it], bfv[jt], acc[it][jt], 0, 0, 0);
    __syncthreads();
  }

#pragma unroll
  for (int it = 0; it < 4; ++it) {
    const int rbase = bm * 128 + wm * 64 + it * 16 + qd * 4;
#pragma unroll
    for (int jt = 0; jt < 4; ++jt) {
      const int cc = bn * 128 + wn * 64 + jt * 16 + ln;
      float bia = 0.f;
      if constexpr (MODE == 2) bia = bias[cc];
#pragma unroll
      for (int rr = 0; rr < 4; ++rr) {
        const int rg = rbase + rr;
        const float v = acc[it][jt][rr];
        if constexpr (MODE == 0) {
          int b = rg >> 12, i = rg & 4095;
          int nch = i >> 6, ic = i & 63;
          int h = cc >> 6, d = cc & 63;
          ((short*)C1v)[(((size_t)(b * 8 + h) * 64 + nch) * 64 + ic) * 64 + d] = f2bf(v * 0.125f);
        } else if constexpr (MODE == 1) {
          int b = rg >> 13, j = rg & 8191;
          int nch = j >> 7, jc = j & 127;
          int d = cc & 63;
          if (cc < 512) {
            int h = cc >> 6;
            ((short*)C1v)[(((size_t)(b * 8 + h) * 64 + nch) * 128 + jc) * 64 + d] = f2bf(v);
          } else {
            int h = (cc - 512) >> 6;
            C2[(((size_t)(b * 8 + h) * 64 + nch) * 128 + jc) * 64 + d] = f2bf(v);
          }
        } else {
          int b = rg >> 12, i = rg & 4095;
          ((float*)C1v)[((size_t)b * 4097 + 1 + i) * 1024 + cc] = v + bia;
        }
      }
    }
  }
}

// ---------------- FALLBACK GEMM (round-3, f32 A staging) --------------------
template <int MODE>
__global__ __launch_bounds__(256, 2) void gemm_k(const void* __restrict__ Av,
                                                 const short* __restrict__ BT,
                                                 const float* __restrict__ bias,
                                                 void* __restrict__ C1v,
                                                 short* __restrict__ C2) {
  constexpr int Ksz = (MODE == 2) ? 512 : 1024;
  __shared__ short As[128 * 40];
  __shared__ short Bs[128 * 40];
  const int t = threadIdx.x;
  const int bm = blockIdx.x, bn = blockIdx.y;
  const int wid = t >> 6, lane = t & 63, qd = lane >> 4, ln = lane & 15;
  const int wm = wid >> 1, wn = wid & 1;

  const f32x4 zf = {0.f, 0.f, 0.f, 0.f};
  f32x4 acc[4][4];
#pragma unroll
  for (int it = 0; it < 4; ++it)
#pragma unroll
    for (int jt = 0; jt < 4; ++jt) acc[it][jt] = zf;

  const int arow = t >> 1;
  const int koff = (t & 1) * 16;
  const float* asrcF = nullptr;
  const short* asrcB = nullptr;
  bool avalid = true;
  {
    int gr = bm * 128 + arow;
    if constexpr (MODE == 0) {
      int b = gr >> 12, i = gr & 4095;
      asrcF = (const float*)Av + ((size_t)b * 4097 + 1 + i) * 1024;
    } else if constexpr (MODE == 1) {
      int b = gr >> 13, j = gr & 8191;
      avalid = (j >= 127);
      asrcF = (const float*)Av + ((size_t)b * 8065 + (j - 127)) * 1024;
    } else {
      asrcB = (const short*)Av + (size_t)gr * 512;
    }
  }
  const short* bsrc = BT + (size_t)(bn * 128 + arow) * Ksz;

  for (int kt = 0; kt < Ksz / 32; ++kt) {
    const int k0 = kt * 32 + koff;
    bf16x8 a0, a1;
    if constexpr (MODE == 2) {
      a0 = *(const bf16x8*)(asrcB + k0);
      a1 = *(const bf16x8*)(asrcB + k0 + 8);
    } else {
      f32x4 f0 = zf, f1 = zf, f2 = zf, f3 = zf;
      if (avalid) {
        f0 = *(const f32x4*)(asrcF + k0);
        f1 = *(const f32x4*)(asrcF + k0 + 4);
        f2 = *(const f32x4*)(asrcF + k0 + 8);
        f3 = *(const f32x4*)(asrcF + k0 + 12);
      }
#pragma unroll
      for (int i = 0; i < 4; ++i) {
        a0[i]     = f2bf_r(f0[i]);
        a0[i + 4] = f2bf_r(f1[i]);
        a1[i]     = f2bf_r(f2[i]);
        a1[i + 4] = f2bf_r(f3[i]);
      }
    }
    bf16x8 b0 = *(const bf16x8*)(bsrc + k0);
    bf16x8 b1 = *(const bf16x8*)(bsrc + k0 + 8);
    *(bf16x8*)&As[arow * 40 + koff] = a0;
    *(bf16x8*)&As[arow * 40 + koff + 8] = a1;
    *(bf16x8*)&Bs[arow * 40 + koff] = b0;
    *(bf16x8*)&Bs[arow * 40 + koff + 8] = b1;
    __syncthreads();
    bf16x8 af[4], bfv[4];
#pragma unroll
    for (int it = 0; it < 4; ++it)
      af[it] = *(const bf16x8*)&As[(wm * 64 + it * 16 + ln) * 40 + qd * 8];
#pragma unroll
    for (int jt = 0; jt < 4; ++jt)
      bfv[jt] = *(const bf16x8*)&Bs[(wn * 64 + jt * 16 + ln) * 40 + qd * 8];
#pragma unroll
    for (int it = 0; it < 4; ++it)
#pragma unroll
      for (int jt = 0; jt < 4; ++jt)
        acc[it][jt] = __builtin_amdgcn_mfma_f32_16x16x32_bf16(af[it], bfv[jt], acc[it][jt], 0, 0, 0);
    __syncthreads();
  }

#pragma unroll
  for (int it = 0; it < 4; ++it) {
    const int rbase = bm * 128 + wm * 64 + it * 16 + qd * 4;
#pragma unroll
    for (int jt = 0; jt < 4; ++jt) {
      const int cc = bn * 128 + wn * 64 + jt * 16 + ln;
      float bia = 0.f;
      if constexpr (MODE == 2) bia = bias[cc];
#pragma unroll
      for (int rr = 0; rr < 4; ++rr) {
        const int rg = rbase + rr;
        const float v = acc[it][jt][rr];
        if constexpr (MODE == 0) {
          int b = rg >> 12, i = rg & 4095;
          int nch = i >> 6, ic = i & 63;
          int h = cc >> 6, d = cc & 63;
          ((short*)C1v)[(((size_t)(b * 8 + h) * 64 + nch) * 64 + ic) * 64 + d] = f2bf(v * 0.125f);
        } else if constexpr (MODE == 1) {
          int b = rg >> 13, j = rg & 8191;
          int nch = j >> 7, jc = j & 127;
          int d = cc & 63;
          if (cc < 512) {
            int h = cc >> 6;
            ((short*)C1v)[(((size_t)(b * 8 + h) * 64 + nch) * 128 + jc) * 64 + d] = f2bf(v);
          } else {
            int h = (cc - 512) >> 6;
            C2[(((size_t)(b * 8 + h) * 64 + nch) * 128 + jc) * 64 + d] = f2bf(v);
          }
        } else {
          int b = rg >> 12, i = rg & 4095;
          ((float*)C1v)[((size_t)b * 4097 + 1 + i) * 1024 + cc] = v + bia;
        }
      }
    }
  }
}

// ---------------- fused attention (sim, softmax, talking-heads, PV) ---------
// R4: grid (b,nch)=256 blocks, 512 thr, wave=head. K/V/null frags register-
// resident; 4 q-groups (16 rows each) looped in-block reusing them.
__global__ __launch_bounds__(512, 2) void attn_kernel(
    const short* __restrict__ qws, const short* __restrict__ kws,
    const short* __restrict__ vws, const float* __restrict__ null_k,
    const float* __restrict__ null_v, const float* __restrict__ W_th,
    const float* __restrict__ b_th, short* __restrict__ ows) {
  __shared__ short P[8 * 16 * 152];

  const int blk = blockIdx.x;            // 256 blocks: (b, nch)
  const int b = blk >> 6;
  const int nch = blk & 63;
  const int tid = threadIdx.x;
  const int wid = tid >> 6;              // head
  const int lane = tid & 63;
  const int qd = lane >> 4, ln = lane & 15;

  const bf16x8 z8 = {0, 0, 0, 0, 0, 0, 0, 0};
  const f32x4 zf = {0.f, 0.f, 0.f, 0.f};

  const short* qb = qws + ((size_t)(b * 8 + wid) * 64 + nch) * 64 * 64;
  const short* kb = kws + ((size_t)(b * 8 + wid) * 64 + nch) * 128 * 64;
  const short* vb = vws + ((size_t)(b * 8 + wid) * 64 + nch) * 128 * 64;

  // ---- K fragments (held across all 4 q-groups)
  bf16x8 kf[8][2];
#pragma unroll
  for (int jt = 0; jt < 8; ++jt)
#pragma unroll
    for (int kk = 0; kk < 2; ++kk)
      kf[jt][kk] = *(const bf16x8*)(kb + (jt * 16 + ln) * 64 + kk * 32 + qd * 8);

  // ---- null-K fragments
  bf16x8 nkf[2];
#pragma unroll
  for (int kk = 0; kk < 2; ++kk) {
    bf16x8 nk = z8;
    if (ln == 0) {
#pragma unroll
      for (int j = 0; j < 8; ++j)
        nk[j] = f2bf(null_k[wid * 64 + kk * 32 + qd * 8 + j]);
    }
    nkf[kk] = nk;
  }

  // ---- V fragments (held across all 4 q-groups)
  bf16x8 vf[4][4];
#pragma unroll
  for (int kk = 0; kk < 4; ++kk)
#pragma unroll
    for (int dt = 0; dt < 4; ++dt) {
      bf16x8 tmp;
#pragma unroll
      for (int jj = 0; jj < 8; ++jj)
        tmp[jj] = vb[(kk * 32 + qd * 8 + jj) * 64 + dt * 16 + ln];
      vf[kk][dt] = tmp;
    }

  // ---- null-V
  float nv[4];
#pragma unroll
  for (int dt = 0; dt < 4; ++dt) nv[dt] = null_v[wid * 64 + dt * 16 + ln];

  // ---- talking-heads weights -> SGPRs (readfirstlane)
  float w[64];
#pragma unroll
  for (int i = 0; i < 64; ++i) {
    union { float f; int i; } u;
    u.f = W_th[i];
    u.i = __builtin_amdgcn_readfirstlane(u.i);
    w[i] = u.f;
  }
  float bt[8];
#pragma unroll
  for (int g = 0; g < 8; ++g) {
    union { float f; int i; } u;
    u.f = b_th[g];
    u.i = __builtin_amdgcn_readfirstlane(u.i);
    bt[g] = u.f;
  }

  for (int qg = 0; qg < 4; ++qg) {
    // ---- QK^T for this 16-row group
    bf16x8 qf[2];
#pragma unroll
    for (int kk = 0; kk < 2; ++kk)
      qf[kk] = *(const bf16x8*)(qb + (qg * 16 + ln) * 64 + kk * 32 + qd * 8);

    f32x4 acc[9];
#pragma unroll
    for (int jt = 0; jt < 9; ++jt) acc[jt] = zf;
#pragma unroll
    for (int jt = 0; jt < 8; ++jt)
#pragma unroll
      for (int kk = 0; kk < 2; ++kk)
        acc[jt] = __builtin_amdgcn_mfma_f32_16x16x32_bf16(qf[kk], kf[jt][kk], acc[jt], 0, 0, 0);
#pragma unroll
    for (int kk = 0; kk < 2; ++kk)
      acc[8] = __builtin_amdgcn_mfma_f32_16x16x32_bf16(qf[kk], nkf[kk], acc[8], 0, 0, 0);

    // ---- softmax per row, write P
#pragma unroll
    for (int rr = 0; rr < 4; ++rr) {
      float v[9];
      float m = -3.0e38f;
#pragma unroll
      for (int jt = 0; jt < 9; ++jt) {
        float x = acc[jt][rr];
        if (jt == 8 && ln != 0) x = -3.0e38f;
        v[jt] = x;
        m = fmaxf(m, x);
      }
#pragma unroll
      for (int s = 1; s < 16; s <<= 1) m = fmaxf(m, __shfl_xor(m, s, 64));
      float sum = 0.f;
#pragma unroll
      for (int jt = 0; jt < 9; ++jt) {
        float e = (jt == 8 && ln != 0) ? 0.f : exp2f((v[jt] - m) * 1.44269504f);
        v[jt] = e;
        sum += e;
      }
#pragma unroll
      for (int s = 1; s < 16; s <<= 1) sum += __shfl_xor(sum, s, 64);
      const float inv = 1.0f / sum;
      const int row = qd * 4 + rr;
#pragma unroll
      for (int jt = 0; jt < 9; ++jt)
        P[(wid * 16 + row) * 152 + jt * 16 + ln] = f2bf(v[jt] * inv);
    }
    __syncthreads();

    // ---- talking-heads mix (across heads, same rows/cols)
    {
      const int r = tid >> 5;
      const int c0 = (tid & 31) * 5;
      for (int c = c0; c < c0 + 5 && c < 129; ++c) {
        float v[8];
#pragma unroll
        for (int h = 0; h < 8; ++h) v[h] = bf2f(P[(h * 16 + r) * 152 + c]);
        float o[8];
#pragma unroll
        for (int g = 0; g < 8; ++g) {
          float s = bt[g];
#pragma unroll
          for (int h = 0; h < 8; ++h) s += w[g * 8 + h] * v[h];
          o[g] = s;
        }
#pragma unroll
        for (int g = 0; g < 8; ++g) P[(g * 16 + r) * 152 + c] = f2bf(o[g]);
      }
    }
    __syncthreads();

    // ---- PV with register-resident V
    f32x4 oacc[4];
#pragma unroll
    for (int dt = 0; dt < 4; ++dt) oacc[dt] = zf;
#pragma unroll
    for (int kk = 0; kk < 4; ++kk) {
      bf16x8 af = *(const bf16x8*)&P[(wid * 16 + ln) * 152 + kk * 32 + qd * 8];
#pragma unroll
      for (int dt = 0; dt < 4; ++dt)
        oacc[dt] = __builtin_amdgcn_mfma_f32_16x16x32_bf16(af, vf[kk][dt], oacc[dt], 0, 0, 0);
    }
    {
#pragma unroll
      for (int rr = 0; rr < 4; ++rr) {
        float p = bf2f(P[(wid * 16 + qd * 4 + rr) * 152 + 128]);
#pragma unroll
        for (int dt = 0; dt < 4; ++dt) oacc[dt][rr] += p * nv[dt];
      }
    }
    const size_t rowbase = (size_t)b * 4096 + nch * 64 + qg * 16;
#pragma unroll
    for (int dt = 0; dt < 4; ++dt)
#pragma unroll
      for (int rr = 0; rr < 4; ++rr)
        ows[(rowbase + qd * 4 + rr) * 512 + wid * 64 + dt * 16 + ln] = f2bf(oacc[dt][rr]);
    __syncthreads();   // protect P before next group's write
  }
}

// ---------------------------------------------------------------------------
extern "C" void kernel_launch(void* const* d_in, const int* in_sizes, int n_in,
                              void* d_out, int out_size, void* d_ws, size_t ws_size,
                              hipStream_t stream) {
  const float* seq   = (const float*)d_in[0];
  const float* ctx   = (const float*)d_in[1];
  const float* Wq    = (const float*)d_in[2];
  const float* Wkv   = (const float*)d_in[3];
  const float* Wout  = (const float*)d_in[4];
  const float* b_out = (const float*)d_in[5];
  const float* nullk = (const float*)d_in[6];
  const float* nullv = (const float*)d_in[7];
  const float* W_th  = (const float*)d_in[8];
  const float* b_th  = (const float*)d_in[9];

  char* ws = (char*)d_ws;
  float* out = (float*)d_out;
  const bool fast = ws_size >= 188743680ull;

  if (fast) {
    short* seqb  = (short*)(ws);
    short* ows   = (short*)(ws);                 // reuses seqb after Q GEMM
    short* ctxb  = (short*)(ws + 33554432);
    short* qws   = (short*)(ws + 100663296);
    short* kws   = (short*)(ws + 117440512);
    short* vws   = (short*)(ws + 150994944);
    short* wqT   = (short*)(ws + 184549376);
    short* wkvT  = (short*)(ws + 185597952);
    short* woutT = (short*)(ws + 187695104);

    hipLaunchKernelGGL(transpose_w, dim3(8192), dim3(256), 0, stream,
                       Wq, Wkv, Wout, wqT, wkvT, woutT);
    hipLaunchKernelGGL(conv_seq, dim3(8192), dim3(256), 0, stream, seq, seqb);
    hipLaunchKernelGGL(conv_ctx, dim3(16384), dim3(256), 0, stream, ctx, ctxb);
    hipLaunchKernelGGL((gemm_fast<0>), dim3(128, 4), dim3(256), 0, stream,
                       seqb, wqT, (const float*)nullptr, (void*)qws, (short*)nullptr);
    hipLaunchKernelGGL((gemm256<1>), dim3(512), dim3(512), 0, stream,
                       ctxb, wkvT, (const float*)nullptr, (void*)kws, vws);
    hipLaunchKernelGGL(attn_kernel, dim3(256), dim3(512), 0, stream,
                       qws, kws, vws, nullk, nullv, W_th, b_th, ows);
    hipLaunchKernelGGL(zero_rows, dim3(16), dim3(256), 0, stream, out);
    hipLaunchKernelGGL((gemm256<2>), dim3(256), dim3(512), 0, stream,
                       ows, woutT, b_out, (void*)out, (short*)nullptr);
  } else {
    short* qws   = (short*)(ws);
    short* kws   = (short*)(ws + 16777216);
    short* vws   = (short*)(ws + 50331648);
    short* ows   = (short*)(ws + 83886080);
    short* wqT   = (short*)(ws + 100663296);
    short* wkvT  = (short*)(ws + 101711872);
    short* woutT = (short*)(ws + 103809024);

    hipLaunchKernelGGL(transpose_w, dim3(8192), dim3(256), 0, stream,
                       Wq, Wkv, Wout, wqT, wkvT, woutT);
    hipLaunchKernelGGL((gemm_k<0>), dim3(128, 4), dim3(256), 0, stream,
                       (const void*)seq, wqT, (const float*)nullptr, (void*)qws, (short*)nullptr);
    hipLaunchKernelGGL((gemm_k<1>), dim3(256, 8), dim3(256), 0, stream,
                       (const void*)ctx, wkvT, (const float*)nullptr, (void*)kws, vws);
    hipLaunchKernelGGL(attn_kernel, dim3(256), dim3(512), 0, stream,
                       qws, kws, vws, nullk, nullv, W_th, b_th, ows);
    hipLaunchKernelGGL(zero_rows, dim3(16), dim3(256), 0, stream, out);
    hipLaunchKernelGGL((gemm_k<2>), dim3(128, 8), dim3(256), 0, stream,
                       (const void*)ows, woutT, b_out, (void*)out, (short*)nullptr);
  }
}